// Round 13
// baseline (129.275 us; speedup 1.0000x reference)
//
#include <hip/hip_runtime.h>
#include <hip/hip_bf16.h>

#define B_ 2
#define T_ 2048
#define E_ 1024
#define NH 16
#define M_ (B_*T_)   // 4096
#define N3E 3072

typedef __attribute__((ext_vector_type(8))) short short8;
typedef __attribute__((ext_vector_type(4))) float f32x4;

__device__ __forceinline__ unsigned short f2bf(float f) {
  unsigned u = __builtin_bit_cast(unsigned, f);
  unsigned r = 0x7FFFu + ((u >> 16) & 1u);
  return (unsigned short)((u + r) >> 16);
}

__device__ __forceinline__ float bf2f(unsigned short s) {
  return __builtin_bit_cast(float, ((unsigned)s) << 16);
}

__device__ __forceinline__ unsigned cvtpk(float a, float b) {
  unsigned r;
  asm("v_cvt_pk_bf16_f32 %0, %1, %2" : "=v"(r) : "v"(a), "v"(b));
  return r;
}

__device__ __forceinline__ float exp2fast(float x) {
  float r;
  asm("v_exp_f32 %0, %1" : "=v"(r) : "v"(x));
  return r;
}

__device__ __forceinline__ void gload16(const void* g, void* l) {
  __builtin_amdgcn_global_load_lds(
      (const __attribute__((address_space(1))) unsigned int*)g,
      (__attribute__((address_space(3))) unsigned int*)l, 16, 0, 0);
}

__device__ __forceinline__ f32x4 mfma16(short8 a, short8 b, f32x4 c) {
  return __builtin_amdgcn_mfma_f32_16x16x32_bf16(a, b, c, 0, 0, 0);
}

// ---- merged prep: cast stacked->bf16, transpose+cast both weights ----
__global__ __launch_bounds__(256) void prep_kernel(
    const float* __restrict__ stacked, const float* __restrict__ w_attn,
    const float* __restrict__ w_proj, unsigned short* __restrict__ Abf,
    unsigned short* __restrict__ WaT, unsigned short* __restrict__ WpT) {
  __shared__ float tile[32][33];
  const int bx = blockIdx.x;
  const int tid = threadIdx.x;
  if (bx < 2048) {
    int i = bx * 256 + tid;
    const float4* p = (const float4*)stacked + (size_t)i * 2;
    float4 a = p[0], b = p[1];
    short8 o;
    o[0] = (short)f2bf(a.x); o[1] = (short)f2bf(a.y);
    o[2] = (short)f2bf(a.z); o[3] = (short)f2bf(a.w);
    o[4] = (short)f2bf(b.x); o[5] = (short)f2bf(b.y);
    o[6] = (short)f2bf(b.z); o[7] = (short)f2bf(b.w);
    *(short8*)(Abf + (size_t)i * 8) = o;
    return;
  }
  const float* in;
  unsigned short* out;
  int R, C, c0, r0;
  if (bx < 5120) {
    int b = bx - 2048;
    in = w_attn; out = WaT; R = E_; C = N3E;
    c0 = (b % 96) * 32; r0 = (b / 96) * 32;
  } else {
    int b = bx - 5120;
    in = w_proj; out = WpT; R = E_; C = E_;
    c0 = (b % 32) * 32; r0 = (b / 32) * 32;
  }
  int tx = tid & 31, ty = tid >> 5;  // 32 x 8
#pragma unroll
  for (int i = 0; i < 4; i++) {
    int r = ty + i * 8;
    tile[r][tx] = in[(size_t)(r0 + r) * C + c0 + tx];
  }
  __syncthreads();
#pragma unroll
  for (int i = 0; i < 4; i++) {
    int r = ty + i * 8;
    out[(size_t)(c0 + r) * R + r0 + tx] = f2bf(tile[tx][r]);
  }
}

// ---- GEMM1 256x192: BK=64, counted-vmcnt 2-barrier pipeline, fused V-T ----
__global__ __launch_bounds__(512, 1) void gemm256(
    const unsigned short* __restrict__ A, const unsigned short* __restrict__ Bt,
    const float* __restrict__ bias, unsigned short* __restrict__ qkvout,
    unsigned short* __restrict__ Vt, int M, int N, int K) {
  __shared__ __attribute__((aligned(16))) unsigned short Asm[2][256 * 64];
  __shared__ __attribute__((aligned(16))) unsigned short Bsm[2][192 * 64];
  const int tid = threadIdx.x;
  const int lane = tid & 63, wid = tid >> 6;
  const int wr = wid >> 2, wcn = wid & 3;  // 2 x 4 wave grid
  const int li = lane & 15, g = lane >> 4;
  const int sw = li & 7;

  const int ntx = N / 192;
  const int nwg = (M >> 8) * ntx;
  const int cpx = nwg >> 3;
  const int logical = (blockIdx.x & 7) * cpx + (blockIdx.x >> 3);
  const int bm = (logical / ntx) << 8;
  const int bn = (logical % ntx) * 192;

  f32x4 acc[8][3] = {};

#define G256_STAGE(kk0, bf)                                                   \
  {                                                                           \
    _Pragma("unroll") for (int p = 0; p < 4; p++) {                           \
      int idx = tid + p * 512;                                                \
      int r = idx >> 3, ch = idx & 7;                                         \
      gload16(A + (size_t)(bm + r) * K + (kk0) + ((ch ^ (r & 7)) << 3),       \
              (char*)&Asm[bf][0] + idx * 16);                                 \
    }                                                                         \
    _Pragma("unroll") for (int p = 0; p < 3; p++) {                           \
      int idx = tid + p * 512;                                                \
      int r = idx >> 3, ch = idx & 7;                                         \
      gload16(Bt + (size_t)(bn + r) * K + (kk0) + ((ch ^ (r & 7)) << 3),      \
              (char*)&Bsm[bf][0] + idx * 16);                                 \
    }                                                                         \
  }

  // prologue: issue K-tile 0 (no wait — covered by loop-top vmcnt+barrier)
  G256_STAGE(0, 0);

  const int NT = K >> 6;  // 16 K-tiles
  for (int t = 0; t < NT; t++) {
    const int buf = t & 1;
    const unsigned short* As = &Asm[buf][0];
    const unsigned short* Bs = &Bsm[buf][0];
    const bool pre = (t + 1 < NT);
    if (pre) G256_STAGE((t + 1) << 6, buf ^ 1);
    // counted wait: only tile-t's 7 loads must be done; t+1's stay in flight
    if (pre)
      asm volatile("s_waitcnt vmcnt(7)" ::: "memory");
    else
      asm volatile("s_waitcnt vmcnt(0)" ::: "memory");
    __syncthreads();
    short8 a[4][2];
#pragma unroll
    for (int ph = 0; ph < 6; ph++) {
      const int mh = ph / 3, nf3 = ph % 3;
      if (nf3 == 0) {
#pragma unroll
        for (int mf = 0; mf < 4; mf++) {
          const int R = wr * 128 + (mh * 4 + mf) * 16 + li;
          a[mf][0] = *(const short8*)&As[R * 64 + ((g ^ sw) << 3)];
          a[mf][1] = *(const short8*)&As[R * 64 + (((4 + g) ^ sw) << 3)];
        }
      }
      const int S = wcn * 48 + nf3 * 16 + li;
      short8 b0 = *(const short8*)&Bs[S * 64 + ((g ^ sw) << 3)];
      short8 b1 = *(const short8*)&Bs[S * 64 + (((4 + g) ^ sw) << 3)];
      __builtin_amdgcn_sched_barrier(0);
      __builtin_amdgcn_s_setprio(1);
#pragma unroll
      for (int mf = 0; mf < 4; mf++) {
        f32x4 c = acc[mh * 4 + mf][nf3];
        c = mfma16(a[mf][0], b0, c);
        c = mfma16(a[mf][1], b1, c);
        acc[mh * 4 + mf][nf3] = c;
      }
      __builtin_amdgcn_s_setprio(0);
      __builtin_amdgcn_sched_barrier(0);
    }
    __syncthreads();  // releases buf for next iteration's issue
  }
#undef G256_STAGE

#pragma unroll
  for (int nf = 0; nf < 3; nf++) {
    int col = bn + wcn * 48 + nf * 16 + li;
    float bs = bias[col];
    if (col < 2 * E_) {
#pragma unroll
      for (int mf = 0; mf < 8; mf++) {
        int row0 = bm + wr * 128 + mf * 16 + g * 4;
#pragma unroll
        for (int r = 0; r < 4; r++)
          qkvout[(size_t)(row0 + r) * N + col] = f2bf(acc[mf][nf][r] + bs);
      }
    } else {
      const int c = col - 2 * E_;
#pragma unroll
      for (int mf = 0; mf < 8; mf++) {
        int row0 = bm + wr * 128 + mf * 16 + g * 4;
        int bq = row0 >> 11, s0 = row0 & 2047;
        uint2 o;
        o.x = cvtpk(acc[mf][nf][0] + bs, acc[mf][nf][1] + bs);
        o.y = cvtpk(acc[mf][nf][2] + bs, acc[mf][nf][3] + bs);
        *(uint2*)&Vt[(size_t)(bq * E_ + c) * T_ + s0] = o;
      }
    }
  }
}

// ---- GEMM2: BK=32, counted-vmcnt 2-barrier pipeline ----
template <int OUTF32>
__global__ __launch_bounds__(256) void gemm_bt(
    const unsigned short* __restrict__ A, const unsigned short* __restrict__ Bt,
    const float* __restrict__ bias, void* __restrict__ outp,
    int M, int N, int K) {
  __shared__ __attribute__((aligned(16))) unsigned short Asm[2][128 * 32];
  __shared__ __attribute__((aligned(16))) unsigned short Bsm[2][128 * 32];
  const int tid = threadIdx.x;
  const int lane = tid & 63;
  const int wid = tid >> 6;
  const int wr = wid >> 1, wc = wid & 1;
  const int li = lane & 15, g = lane >> 4;

  const int ntx = N >> 7;
  const int nwg = (M >> 7) * ntx;
  const int cpx = nwg >> 3;
  const int logical = (blockIdx.x & 7) * cpx + (blockIdx.x >> 3);
  const int bm = (logical / ntx) << 7;
  const int bn = (logical % ntx) << 7;

  f32x4 acc[4][4] = {};

  const int srow = tid >> 2;
  const int scol = (tid & 3) * 8;
  const unsigned short* Ag = A + (size_t)(bm + srow) * K + scol;
  const unsigned short* Bg = Bt + (size_t)(bn + srow) * K + scol;
  const int ldsoff = tid * 16;

#define GBT_STAGE(kk0, bf)                                                    \
  {                                                                           \
    gload16(Ag + (kk0), (char*)&Asm[bf][0] + ldsoff);                         \
    gload16(Ag + (size_t)64 * K + (kk0), (char*)&Asm[bf][0] + ldsoff + 4096); \
    gload16(Bg + (kk0), (char*)&Bsm[bf][0] + ldsoff);                         \
    gload16(Bg + (size_t)64 * K + (kk0), (char*)&Bsm[bf][0] + ldsoff + 4096); \
  }

  GBT_STAGE(0, 0);

  int cur = 0;
  for (int k0 = 0; k0 < K; k0 += 32) {
    const bool pre = (k0 + 32 < K);
    if (pre) GBT_STAGE(k0 + 32, cur ^ 1);
    if (pre)
      asm volatile("s_waitcnt vmcnt(4)" ::: "memory");
    else
      asm volatile("s_waitcnt vmcnt(0)" ::: "memory");
    __syncthreads();
    short8 af[4], bf[4];
#pragma unroll
    for (int i = 0; i < 4; i++)
      af[i] = *(const short8*)&Asm[cur][(wr * 64 + i * 16 + li) * 32 + g * 8];
#pragma unroll
    for (int j = 0; j < 4; j++)
      bf[j] = *(const short8*)&Bsm[cur][(wc * 64 + j * 16 + li) * 32 + g * 8];
    __builtin_amdgcn_s_setprio(1);
#pragma unroll
    for (int i = 0; i < 4; i++)
#pragma unroll
      for (int j = 0; j < 4; j++)
        acc[i][j] = __builtin_amdgcn_mfma_f32_16x16x32_bf16(af[i], bf[j],
                                                            acc[i][j], 0, 0, 0);
    __builtin_amdgcn_s_setprio(0);
    __syncthreads();
    cur ^= 1;
  }
#undef GBT_STAGE

#pragma unroll
  for (int j = 0; j < 4; j++) {
    int col = bn + wc * 64 + j * 16 + li;
    float bs = bias[col];
#pragma unroll
    for (int i = 0; i < 4; i++) {
      int row0 = bm + wr * 64 + i * 16 + g * 4;
#pragma unroll
      for (int r = 0; r < 4; r++) {
        float v = acc[i][j][r] + bs;
        if (OUTF32)
          ((float*)outp)[(size_t)(row0 + r) * N + col] = v;
        else
          ((unsigned short*)outp)[(size_t)(row0 + r) * N + col] = f2bf(v);
      }
    }
  }
}

// ---- flash attention (R11 structure + counted-vmcnt schedule) ----
__device__ __forceinline__ void attn_tile(
    const unsigned short* Ksm, const unsigned short* Vts,
    unsigned short (*PsmW)[64], short8 qf0, short8 qf1,
    float& m2, float& l2, f32x4* O, int qrel, bool diag, int li, int g) {
  f32x4 S[4];
  __builtin_amdgcn_s_setprio(1);
#pragma unroll
  for (int ct = 0; ct < 4; ct++) {
    int r = ct * 16 + li;
    int sw = r & 7;
    short8 k0f = *(const short8*)&Ksm[r * 64 + ((g ^ sw) << 3)];
    short8 k1f = *(const short8*)&Ksm[r * 64 + (((g + 4) ^ sw) << 3)];
    f32x4 z = {0.f, 0.f, 0.f, 0.f};
    z = mfma16(k0f, qf0, z);
    z = mfma16(k1f, qf1, z);
    S[ct] = z;
  }
  __builtin_amdgcn_s_setprio(0);

  if (diag) {
#pragma unroll
    for (int ct = 0; ct < 4; ct++)
#pragma unroll
      for (int r = 0; r < 4; r++)
        if (ct * 16 + g * 4 + r > qrel) S[ct][r] = -30000.f;
  }

  float tmax = S[0][0];
#pragma unroll
  for (int ct = 0; ct < 4; ct++)
#pragma unroll
    for (int r = 0; r < 4; r++) tmax = fmaxf(tmax, S[ct][r]);
  tmax = fmaxf(tmax, __shfl_xor(tmax, 16));
  tmax = fmaxf(tmax, __shfl_xor(tmax, 32));

  if (__any(tmax > m2 + 11.5f)) {
    float mn = fmaxf(m2, tmax);
    float cs = exp2fast(m2 - mn);
    l2 *= cs;
#pragma unroll
    for (int c2 = 0; c2 < 4; c2++)
#pragma unroll
      for (int r = 0; r < 4; r++) O[c2][r] *= cs;
    m2 = mn;
  }

  float rsum = 0.f;
#pragma unroll
  for (int ct = 0; ct < 4; ct++) {
    float p0 = exp2fast(S[ct][0] - m2);
    float p1 = exp2fast(S[ct][1] - m2);
    float p2 = exp2fast(S[ct][2] - m2);
    float p3 = exp2fast(S[ct][3] - m2);
    rsum += (p0 + p1) + (p2 + p3);
    uint2 pk;
    pk.x = cvtpk(p0, p1);
    pk.y = cvtpk(p2, p3);
    int pc = (2 * ct + (g >> 1)) ^ (li & 7);
    *(uint2*)&PsmW[li][pc * 8 + (g & 1) * 4] = pk;
  }
  rsum += __shfl_xor(rsum, 16);
  rsum += __shfl_xor(rsum, 32);
  l2 += rsum;

  __builtin_amdgcn_s_setprio(1);
#pragma unroll
  for (int kk = 0; kk < 2; kk++) {
    short8 pf = *(const short8*)&PsmW[li][((4 * kk + g) ^ (li & 7)) * 8];
#pragma unroll
    for (int c2 = 0; c2 < 4; c2++) {
      int d = c2 * 16 + li;
      short8 vf = *(const short8*)&Vts[d * 64 + (((kk * 4 + g) ^ (li & 7)) << 3)];
      O[c2] = mfma16(vf, pf, O[c2]);
    }
  }
  __builtin_amdgcn_s_setprio(0);
}

__global__ __launch_bounds__(256) void attn_kernel(
    const unsigned short* __restrict__ qkv, const unsigned short* __restrict__ Vt,
    unsigned short* __restrict__ aout) {
  const int pair = blockIdx.x;  // 0..15
  const int h = blockIdx.y, b = blockIdx.z;
  const int qa = pair, qb = (T_ / 64 - 1) - pair;
  const int tid = threadIdx.x, lane = tid & 63, w = tid >> 6;
  const int li = lane & 15, g = lane >> 4;

  __shared__ __attribute__((aligned(16))) unsigned short Ksm[2][64 * 64];
  __shared__ __attribute__((aligned(16))) unsigned short Vts[2][64 * 64];
  __shared__ __attribute__((aligned(16))) unsigned short Psm[4][16][64];

  const size_t rs = 3 * E_;
  const unsigned short* base = qkv + (size_t)b * T_ * rs + h * 64;
  const unsigned short* Kg = base + E_;
  const unsigned short* Vtg = Vt + (size_t)(b * E_ + h * 64) * T_;

  const float QSC = 0.18033688f;  // 0.125 * log2(e)
  short8 qfa0, qfa1, qfb0, qfb1;
  {
    const unsigned short* qrow = base + (size_t)(qa * 64 + w * 16 + li) * rs;
    short8 v0 = *(const short8*)(qrow + g * 8);
    short8 v1 = *(const short8*)(qrow + 32 + g * 8);
    qrow = base + (size_t)(qb * 64 + w * 16 + li) * rs;
    short8 v2 = *(const short8*)(qrow + g * 8);
    short8 v3 = *(const short8*)(qrow + 32 + g * 8);
#pragma unroll
    for (int j = 0; j < 8; j++) {
      qfa0[j] = (short)f2bf(bf2f((unsigned short)v0[j]) * QSC);
      qfa1[j] = (short)f2bf(bf2f((unsigned short)v1[j]) * QSC);
      qfb0[j] = (short)f2bf(bf2f((unsigned short)v2[j]) * QSC);
      qfb1[j] = (short)f2bf(bf2f((unsigned short)v3[j]) * QSC);
    }
  }

  float ma = -1e30f, la = 0.f, mb = -1e30f, lb = 0.f;
  f32x4 Oa[4] = {}, Ob[4] = {};

#define ATT_STAGE(kv, bf)                                                     \
  {                                                                           \
    _Pragma("unroll") for (int p = 0; p < 2; p++) {                           \
      int idx = tid + p * 256;                                                \
      int r = idx >> 3, ch = idx & 7;                                         \
      int sc = (ch ^ (r & 7)) * 8;                                            \
      gload16(Kg + (size_t)((kv)*64 + r) * rs + sc,                           \
              (char*)&Ksm[bf][0] + idx * 16);                                 \
      gload16(Vtg + (size_t)r * T_ + (kv)*64 + sc,                            \
              (char*)&Vts[bf][0] + idx * 16);                                 \
    }                                                                         \
  }

  ATT_STAGE(0, 0);

  const int nt = qb + 1;
  for (int kv = 0; kv < nt; kv++) {
    const int cur = kv & 1, nxt = cur ^ 1;
    const bool pre = (kv + 1 < nt);
    if (pre) ATT_STAGE(kv + 1, nxt);
    if (pre)
      asm volatile("s_waitcnt vmcnt(4)" ::: "memory");
    else
      asm volatile("s_waitcnt vmcnt(0)" ::: "memory");
    __syncthreads();

    attn_tile(&Ksm[cur][0], &Vts[cur][0], Psm[w], qfb0, qfb1, mb, lb, Ob,
              qb * 64 + w * 16 + li - kv * 64, kv == qb, li, g);
    if (kv <= qa)
      attn_tile(&Ksm[cur][0], &Vts[cur][0], Psm[w], qfa0, qfa1, ma, la, Oa,
                qa * 64 + w * 16 + li - kv * 64, kv == qa, li, g);

    __syncthreads();
  }
#undef ATT_STAGE

  const float inva = 1.f / la, invb = 1.f / lb;
  const int rowa = b * T_ + qa * 64 + w * 16 + li;
  const int rowb = b * T_ + qb * 64 + w * 16 + li;
#pragma unroll
  for (int c2 = 0; c2 < 4; c2++) {
    uint2 oa, ob;
    oa.x = cvtpk(Oa[c2][0] * inva, Oa[c2][1] * inva);
    oa.y = cvtpk(Oa[c2][2] * inva, Oa[c2][3] * inva);
    ob.x = cvtpk(Ob[c2][0] * invb, Ob[c2][1] * invb);
    ob.y = cvtpk(Ob[c2][2] * invb, Ob[c2][3] * invb);
    *(uint2*)&aout[(size_t)rowa * E_ + h * 64 + c2 * 16 + g * 4] = oa;
    *(uint2*)&aout[(size_t)rowb * E_ + h * 64 + c2 * 16 + g * 4] = ob;
  }
}

extern "C" void kernel_launch(void* const* d_in, const int* in_sizes, int n_in,
                              void* d_out, int out_size, void* d_ws,
                              size_t ws_size, hipStream_t stream) {
  const float* stacked = (const float*)d_in[0];
  const float* w_attn = (const float*)d_in[1];
  const float* b_attn = (const float*)d_in[2];
  const float* w_proj = (const float*)d_in[3];
  const float* b_proj = (const float*)d_in[4];
  float* out = (float*)d_out;

  unsigned short* Abf = (unsigned short*)d_ws;            // 4096x1024 bf16
  unsigned short* WaT = Abf + (size_t)M_ * E_;            // 3072x1024 bf16
  unsigned short* WpT = WaT + (size_t)N3E * E_;            // 1024x1024 bf16
  unsigned short* qkv = WpT + (size_t)E_ * E_;            // 4096x3072 bf16
  unsigned short* aout = qkv + (size_t)M_ * N3E;          // 4096x1024 bf16
  unsigned short* Vt = aout + (size_t)M_ * E_;            // 2x1024x2048 bf16

  prep_kernel<<<6144, 256, 0, stream>>>(stacked, w_attn, w_proj, Abf, WaT, WpT);
  gemm256<<<(M_ / 256) * (N3E / 192), 512, 0, stream>>>(Abf, WaT, b_attn, qkv,
                                                        Vt, M_, N3E, E_);
  attn_kernel<<<dim3(T_ / 128, NH, B_), 256, 0, stream>>>(qkv, Vt, aout);
  gemm_bt<1><<<(M_ / 128) * (E_ / 128), 256, 0, stream>>>(aout, WpT, b_proj,
                                                          out, M_, E_, E_);
}

// Round 14
// 113.614 us; speedup vs baseline: 1.1378x; 1.1378x over previous
//
#include <hip/hip_runtime.h>
#include <hip/hip_bf16.h>

#define B_ 2
#define T_ 2048
#define E_ 1024
#define NH 16
#define M_ (B_*T_)   // 4096
#define N3E 3072

typedef __attribute__((ext_vector_type(8))) short short8;
typedef __attribute__((ext_vector_type(4))) float f32x4;

__device__ __forceinline__ unsigned short f2bf(float f) {
  unsigned u = __builtin_bit_cast(unsigned, f);
  unsigned r = 0x7FFFu + ((u >> 16) & 1u);
  return (unsigned short)((u + r) >> 16);
}

__device__ __forceinline__ float bf2f(unsigned short s) {
  return __builtin_bit_cast(float, ((unsigned)s) << 16);
}

__device__ __forceinline__ unsigned cvtpk(float a, float b) {
  unsigned r;
  asm("v_cvt_pk_bf16_f32 %0, %1, %2" : "=v"(r) : "v"(a), "v"(b));
  return r;
}

__device__ __forceinline__ float exp2fast(float x) {
  float r;
  asm("v_exp_f32 %0, %1" : "=v"(r) : "v"(x));
  return r;
}

__device__ __forceinline__ void gload16(const void* g, void* l) {
  __builtin_amdgcn_global_load_lds(
      (const __attribute__((address_space(1))) unsigned int*)g,
      (__attribute__((address_space(3))) unsigned int*)l, 16, 0, 0);
}

__device__ __forceinline__ f32x4 mfma16(short8 a, short8 b, f32x4 c) {
  return __builtin_amdgcn_mfma_f32_16x16x32_bf16(a, b, c, 0, 0, 0);
}

// ---- merged prep: cast stacked->bf16, transpose+cast both weights ----
__global__ __launch_bounds__(256) void prep_kernel(
    const float* __restrict__ stacked, const float* __restrict__ w_attn,
    const float* __restrict__ w_proj, unsigned short* __restrict__ Abf,
    unsigned short* __restrict__ WaT, unsigned short* __restrict__ WpT) {
  __shared__ float tile[32][33];
  const int bx = blockIdx.x;
  const int tid = threadIdx.x;
  if (bx < 2048) {
    int i = bx * 256 + tid;
    const float4* p = (const float4*)stacked + (size_t)i * 2;
    float4 a = p[0], b = p[1];
    short8 o;
    o[0] = (short)f2bf(a.x); o[1] = (short)f2bf(a.y);
    o[2] = (short)f2bf(a.z); o[3] = (short)f2bf(a.w);
    o[4] = (short)f2bf(b.x); o[5] = (short)f2bf(b.y);
    o[6] = (short)f2bf(b.z); o[7] = (short)f2bf(b.w);
    *(short8*)(Abf + (size_t)i * 8) = o;
    return;
  }
  const float* in;
  unsigned short* out;
  int R, C, c0, r0;
  if (bx < 5120) {
    int b = bx - 2048;
    in = w_attn; out = WaT; R = E_; C = N3E;
    c0 = (b % 96) * 32; r0 = (b / 96) * 32;
  } else {
    int b = bx - 5120;
    in = w_proj; out = WpT; R = E_; C = E_;
    c0 = (b % 32) * 32; r0 = (b / 32) * 32;
  }
  int tx = tid & 31, ty = tid >> 5;  // 32 x 8
#pragma unroll
  for (int i = 0; i < 4; i++) {
    int r = ty + i * 8;
    tile[r][tx] = in[(size_t)(r0 + r) * C + c0 + tx];
  }
  __syncthreads();
#pragma unroll
  for (int i = 0; i < 4; i++) {
    int r = ty + i * 8;
    out[(size_t)(c0 + r) * R + r0 + tx] = f2bf(tile[tx][r]);
  }
}

// ---- GEMM1 256x192: BK=64, top-issued prefetch, fused V-transpose ----
__global__ __launch_bounds__(512, 1) void gemm256(
    const unsigned short* __restrict__ A, const unsigned short* __restrict__ Bt,
    const float* __restrict__ bias, unsigned short* __restrict__ qkvout,
    unsigned short* __restrict__ Vt, int M, int N, int K) {
  __shared__ __attribute__((aligned(16))) unsigned short Asm[2][256 * 64];
  __shared__ __attribute__((aligned(16))) unsigned short Bsm[2][192 * 64];
  const int tid = threadIdx.x;
  const int lane = tid & 63, wid = tid >> 6;
  const int wr = wid >> 2, wcn = wid & 3;  // 2 x 4 wave grid
  const int li = lane & 15, g = lane >> 4;
  const int sw = li & 7;

  const int ntx = N / 192;
  const int nwg = (M >> 8) * ntx;
  const int cpx = nwg >> 3;
  const int logical = (blockIdx.x & 7) * cpx + (blockIdx.x >> 3);
  const int bm = (logical / ntx) << 8;
  const int bn = (logical % ntx) * 192;

  f32x4 acc[8][3] = {};

  // prologue: stage K-tile 0 into buf 0
#pragma unroll
  for (int p = 0; p < 4; p++) {
    int idx = tid + p * 512;
    int r = idx >> 3, ch = idx & 7;
    gload16(A + (size_t)(bm + r) * K + ((ch ^ (r & 7)) << 3),
            (char*)&Asm[0][0] + idx * 16);
  }
#pragma unroll
  for (int p = 0; p < 3; p++) {
    int idx = tid + p * 512;
    int r = idx >> 3, ch = idx & 7;
    gload16(Bt + (size_t)(bn + r) * K + ((ch ^ (r & 7)) << 3),
            (char*)&Bsm[0][0] + idx * 16);
  }
  asm volatile("s_waitcnt vmcnt(0)" ::: "memory");
  __syncthreads();

  const int NT = K >> 6;  // 16 K-tiles
  for (int t = 0; t < NT; t++) {
    const int buf = t & 1;
    const unsigned short* As = &Asm[buf][0];
    const unsigned short* Bs = &Bsm[buf][0];
    const int kn = (t + 1) << 6;
    const bool pre = (t + 1 < NT);
    // top-issued prefetch: loads get the whole iteration to land
    if (pre) {
#pragma unroll
      for (int p = 0; p < 4; p++) {
        int idx = tid + p * 512;
        int r = idx >> 3, ch = idx & 7;
        gload16(A + (size_t)(bm + r) * K + kn + ((ch ^ (r & 7)) << 3),
                (char*)&Asm[buf ^ 1][0] + idx * 16);
      }
#pragma unroll
      for (int p = 0; p < 3; p++) {
        int idx = tid + p * 512;
        int r = idx >> 3, ch = idx & 7;
        gload16(Bt + (size_t)(bn + r) * K + kn + ((ch ^ (r & 7)) << 3),
                (char*)&Bsm[buf ^ 1][0] + idx * 16);
      }
    }
    short8 a[4][2];
#pragma unroll
    for (int ph = 0; ph < 6; ph++) {
      const int mh = ph / 3, nf3 = ph % 3;
      if (nf3 == 0) {
#pragma unroll
        for (int mf = 0; mf < 4; mf++) {
          const int R = wr * 128 + (mh * 4 + mf) * 16 + li;
          a[mf][0] = *(const short8*)&As[R * 64 + ((g ^ sw) << 3)];
          a[mf][1] = *(const short8*)&As[R * 64 + (((4 + g) ^ sw) << 3)];
        }
      }
      const int S = wcn * 48 + nf3 * 16 + li;
      short8 b0 = *(const short8*)&Bs[S * 64 + ((g ^ sw) << 3)];
      short8 b1 = *(const short8*)&Bs[S * 64 + (((4 + g) ^ sw) << 3)];
      __builtin_amdgcn_sched_barrier(0);
      __builtin_amdgcn_s_setprio(1);
#pragma unroll
      for (int mf = 0; mf < 4; mf++) {
        f32x4 c = acc[mh * 4 + mf][nf3];
        c = mfma16(a[mf][0], b0, c);
        c = mfma16(a[mf][1], b1, c);
        acc[mh * 4 + mf][nf3] = c;
      }
      __builtin_amdgcn_s_setprio(0);
      __builtin_amdgcn_sched_barrier(0);
    }
    asm volatile("s_waitcnt vmcnt(0)" ::: "memory");
    __syncthreads();
  }

#pragma unroll
  for (int nf = 0; nf < 3; nf++) {
    int col = bn + wcn * 48 + nf * 16 + li;
    float bs = bias[col];
    if (col < 2 * E_) {
#pragma unroll
      for (int mf = 0; mf < 8; mf++) {
        int row0 = bm + wr * 128 + mf * 16 + g * 4;
#pragma unroll
        for (int r = 0; r < 4; r++)
          qkvout[(size_t)(row0 + r) * N + col] = f2bf(acc[mf][nf][r] + bs);
      }
    } else {
      const int c = col - 2 * E_;
#pragma unroll
      for (int mf = 0; mf < 8; mf++) {
        int row0 = bm + wr * 128 + mf * 16 + g * 4;
        int bq = row0 >> 11, s0 = row0 & 2047;
        uint2 o;
        o.x = cvtpk(acc[mf][nf][0] + bs, acc[mf][nf][1] + bs);
        o.y = cvtpk(acc[mf][nf][2] + bs, acc[mf][nf][3] + bs);
        *(uint2*)&Vt[(size_t)(bq * E_ + c) * T_ + s0] = o;
      }
    }
  }
}

// ---- GEMM2: BK=32, 2-phase prefetch (issue-top, drain-end), XCD swizzle ----
template <int OUTF32>
__global__ __launch_bounds__(256) void gemm_bt(
    const unsigned short* __restrict__ A, const unsigned short* __restrict__ Bt,
    const float* __restrict__ bias, void* __restrict__ outp,
    int M, int N, int K) {
  __shared__ __attribute__((aligned(16))) unsigned short Asm[2][128 * 32];
  __shared__ __attribute__((aligned(16))) unsigned short Bsm[2][128 * 32];
  const int tid = threadIdx.x;
  const int lane = tid & 63;
  const int wid = tid >> 6;
  const int wr = wid >> 1, wc = wid & 1;
  const int li = lane & 15, g = lane >> 4;

  const int ntx = N >> 7;
  const int nwg = (M >> 7) * ntx;
  const int cpx = nwg >> 3;
  const int logical = (blockIdx.x & 7) * cpx + (blockIdx.x >> 3);
  const int bm = (logical / ntx) << 7;
  const int bn = (logical % ntx) << 7;

  f32x4 acc[4][4] = {};

  const int srow = tid >> 2;
  const int scol = (tid & 3) * 8;
  const unsigned short* Ag = A + (size_t)(bm + srow) * K + scol;
  const unsigned short* Bg = Bt + (size_t)(bn + srow) * K + scol;
  const int ldsoff = tid * 16;

  gload16(Ag, (char*)&Asm[0][0] + ldsoff);
  gload16(Ag + (size_t)64 * K, (char*)&Asm[0][0] + ldsoff + 4096);
  gload16(Bg, (char*)&Bsm[0][0] + ldsoff);
  gload16(Bg + (size_t)64 * K, (char*)&Bsm[0][0] + ldsoff + 4096);
  asm volatile("s_waitcnt vmcnt(0)" ::: "memory");
  __syncthreads();

  int cur = 0;
  for (int k0 = 0; k0 < K; k0 += 32) {
    const bool pre = (k0 + 32 < K);
    if (pre) {
      const int k1 = k0 + 32;
      gload16(Ag + k1, (char*)&Asm[cur ^ 1][0] + ldsoff);
      gload16(Ag + (size_t)64 * K + k1,
              (char*)&Asm[cur ^ 1][0] + ldsoff + 4096);
      gload16(Bg + k1, (char*)&Bsm[cur ^ 1][0] + ldsoff);
      gload16(Bg + (size_t)64 * K + k1,
              (char*)&Bsm[cur ^ 1][0] + ldsoff + 4096);
    }
    short8 af[4], bf[4];
#pragma unroll
    for (int i = 0; i < 4; i++)
      af[i] = *(const short8*)&Asm[cur][(wr * 64 + i * 16 + li) * 32 + g * 8];
#pragma unroll
    for (int j = 0; j < 4; j++)
      bf[j] = *(const short8*)&Bsm[cur][(wc * 64 + j * 16 + li) * 32 + g * 8];
    __builtin_amdgcn_s_setprio(1);
#pragma unroll
    for (int i = 0; i < 4; i++)
#pragma unroll
      for (int j = 0; j < 4; j++)
        acc[i][j] = __builtin_amdgcn_mfma_f32_16x16x32_bf16(af[i], bf[j],
                                                            acc[i][j], 0, 0, 0);
    __builtin_amdgcn_s_setprio(0);
    if (pre) asm volatile("s_waitcnt vmcnt(0)" ::: "memory");
    __syncthreads();
    cur ^= 1;
  }

#pragma unroll
  for (int j = 0; j < 4; j++) {
    int col = bn + wc * 64 + j * 16 + li;
    float bs = bias[col];
#pragma unroll
    for (int i = 0; i < 4; i++) {
      int row0 = bm + wr * 64 + i * 16 + g * 4;
#pragma unroll
      for (int r = 0; r < 4; r++) {
        float v = acc[i][j][r] + bs;
        if (OUTF32)
          ((float*)outp)[(size_t)(row0 + r) * N + col] = v;
        else
          ((unsigned short*)outp)[(size_t)(row0 + r) * N + col] = f2bf(v);
      }
    }
  }
}

// ---- flash attention (R11, proven 48.8us): paired q-tiles, V pre-T ----
__device__ __forceinline__ void attn_tile(
    const unsigned short* Ksm, const unsigned short* Vts,
    unsigned short (*PsmW)[64], short8 qf0, short8 qf1,
    float& m2, float& l2, f32x4* O, int qrel, bool diag, int li, int g) {
  f32x4 S[4];
  __builtin_amdgcn_s_setprio(1);
#pragma unroll
  for (int ct = 0; ct < 4; ct++) {
    int r = ct * 16 + li;
    int sw = r & 7;
    short8 k0f = *(const short8*)&Ksm[r * 64 + ((g ^ sw) << 3)];
    short8 k1f = *(const short8*)&Ksm[r * 64 + (((g + 4) ^ sw) << 3)];
    f32x4 z = {0.f, 0.f, 0.f, 0.f};
    z = mfma16(k0f, qf0, z);
    z = mfma16(k1f, qf1, z);
    S[ct] = z;
  }
  __builtin_amdgcn_s_setprio(0);

  if (diag) {
#pragma unroll
    for (int ct = 0; ct < 4; ct++)
#pragma unroll
      for (int r = 0; r < 4; r++)
        if (ct * 16 + g * 4 + r > qrel) S[ct][r] = -30000.f;
  }

  float tmax = S[0][0];
#pragma unroll
  for (int ct = 0; ct < 4; ct++)
#pragma unroll
    for (int r = 0; r < 4; r++) tmax = fmaxf(tmax, S[ct][r]);
  tmax = fmaxf(tmax, __shfl_xor(tmax, 16));
  tmax = fmaxf(tmax, __shfl_xor(tmax, 32));

  if (__any(tmax > m2 + 11.5f)) {
    float mn = fmaxf(m2, tmax);
    float cs = exp2fast(m2 - mn);
    l2 *= cs;
#pragma unroll
    for (int c2 = 0; c2 < 4; c2++)
#pragma unroll
      for (int r = 0; r < 4; r++) O[c2][r] *= cs;
    m2 = mn;
  }

  float rsum = 0.f;
#pragma unroll
  for (int ct = 0; ct < 4; ct++) {
    float p0 = exp2fast(S[ct][0] - m2);
    float p1 = exp2fast(S[ct][1] - m2);
    float p2 = exp2fast(S[ct][2] - m2);
    float p3 = exp2fast(S[ct][3] - m2);
    rsum += (p0 + p1) + (p2 + p3);
    uint2 pk;
    pk.x = cvtpk(p0, p1);
    pk.y = cvtpk(p2, p3);
    int pc = (2 * ct + (g >> 1)) ^ (li & 7);
    *(uint2*)&PsmW[li][pc * 8 + (g & 1) * 4] = pk;
  }
  rsum += __shfl_xor(rsum, 16);
  rsum += __shfl_xor(rsum, 32);
  l2 += rsum;

  __builtin_amdgcn_s_setprio(1);
#pragma unroll
  for (int kk = 0; kk < 2; kk++) {
    short8 pf = *(const short8*)&PsmW[li][((4 * kk + g) ^ (li & 7)) * 8];
#pragma unroll
    for (int c2 = 0; c2 < 4; c2++) {
      int d = c2 * 16 + li;
      short8 vf = *(const short8*)&Vts[d * 64 + (((kk * 4 + g) ^ (li & 7)) << 3)];
      O[c2] = mfma16(vf, pf, O[c2]);
    }
  }
  __builtin_amdgcn_s_setprio(0);
}

__global__ __launch_bounds__(256) void attn_kernel(
    const unsigned short* __restrict__ qkv, const unsigned short* __restrict__ Vt,
    unsigned short* __restrict__ aout) {
  const int pair = blockIdx.x;  // 0..15
  const int h = blockIdx.y, b = blockIdx.z;
  const int qa = pair, qb = (T_ / 64 - 1) - pair;
  const int tid = threadIdx.x, lane = tid & 63, w = tid >> 6;
  const int li = lane & 15, g = lane >> 4;

  __shared__ __attribute__((aligned(16))) unsigned short Ksm[2][64 * 64];
  __shared__ __attribute__((aligned(16))) unsigned short Vts[2][64 * 64];
  __shared__ __attribute__((aligned(16))) unsigned short Psm[4][16][64];

  const size_t rs = 3 * E_;
  const unsigned short* base = qkv + (size_t)b * T_ * rs + h * 64;
  const unsigned short* Kg = base + E_;
  const unsigned short* Vtg = Vt + (size_t)(b * E_ + h * 64) * T_;

  const float QSC = 0.18033688f;  // 0.125 * log2(e)
  short8 qfa0, qfa1, qfb0, qfb1;
  {
    const unsigned short* qrow = base + (size_t)(qa * 64 + w * 16 + li) * rs;
    short8 v0 = *(const short8*)(qrow + g * 8);
    short8 v1 = *(const short8*)(qrow + 32 + g * 8);
    qrow = base + (size_t)(qb * 64 + w * 16 + li) * rs;
    short8 v2 = *(const short8*)(qrow + g * 8);
    short8 v3 = *(const short8*)(qrow + 32 + g * 8);
#pragma unroll
    for (int j = 0; j < 8; j++) {
      qfa0[j] = (short)f2bf(bf2f((unsigned short)v0[j]) * QSC);
      qfa1[j] = (short)f2bf(bf2f((unsigned short)v1[j]) * QSC);
      qfb0[j] = (short)f2bf(bf2f((unsigned short)v2[j]) * QSC);
      qfb1[j] = (short)f2bf(bf2f((unsigned short)v3[j]) * QSC);
    }
  }

  float ma = -1e30f, la = 0.f, mb = -1e30f, lb = 0.f;
  f32x4 Oa[4] = {}, Ob[4] = {};

#pragma unroll
  for (int p = 0; p < 2; p++) {
    int idx = tid + p * 256;
    int r = idx >> 3, ch = idx & 7;
    int sc = (ch ^ (r & 7)) * 8;
    gload16(Kg + (size_t)r * rs + sc, (char*)&Ksm[0][0] + idx * 16);
    gload16(Vtg + (size_t)r * T_ + sc, (char*)&Vts[0][0] + idx * 16);
  }
  asm volatile("s_waitcnt vmcnt(0)" ::: "memory");
  __syncthreads();

  const int nt = qb + 1;
  for (int kv = 0; kv < nt; kv++) {
    const int cur = kv & 1, nxt = cur ^ 1;
    const bool pre = (kv + 1 < nt);
    if (pre) {
      const int s1 = (kv + 1) * 64;
#pragma unroll
      for (int p = 0; p < 2; p++) {
        int idx = tid + p * 256;
        int r = idx >> 3, ch = idx & 7;
        int sc = (ch ^ (r & 7)) * 8;
        gload16(Kg + (size_t)(s1 + r) * rs + sc,
                (char*)&Ksm[nxt][0] + idx * 16);
        gload16(Vtg + (size_t)r * T_ + s1 + sc,
                (char*)&Vts[nxt][0] + idx * 16);
      }
    }

    attn_tile(&Ksm[cur][0], &Vts[cur][0], Psm[w], qfb0, qfb1, mb, lb, Ob,
              qb * 64 + w * 16 + li - kv * 64, kv == qb, li, g);
    if (kv <= qa)
      attn_tile(&Ksm[cur][0], &Vts[cur][0], Psm[w], qfa0, qfa1, ma, la, Oa,
                qa * 64 + w * 16 + li - kv * 64, kv == qa, li, g);

    asm volatile("s_waitcnt vmcnt(0)" ::: "memory");
    __syncthreads();
  }

  const float inva = 1.f / la, invb = 1.f / lb;
  const int rowa = b * T_ + qa * 64 + w * 16 + li;
  const int rowb = b * T_ + qb * 64 + w * 16 + li;
#pragma unroll
  for (int c2 = 0; c2 < 4; c2++) {
    uint2 oa, ob;
    oa.x = cvtpk(Oa[c2][0] * inva, Oa[c2][1] * inva);
    oa.y = cvtpk(Oa[c2][2] * inva, Oa[c2][3] * inva);
    ob.x = cvtpk(Ob[c2][0] * invb, Ob[c2][1] * invb);
    ob.y = cvtpk(Ob[c2][2] * invb, Ob[c2][3] * invb);
    *(uint2*)&aout[(size_t)rowa * E_ + h * 64 + c2 * 16 + g * 4] = oa;
    *(uint2*)&aout[(size_t)rowb * E_ + h * 64 + c2 * 16 + g * 4] = ob;
  }
}

extern "C" void kernel_launch(void* const* d_in, const int* in_sizes, int n_in,
                              void* d_out, int out_size, void* d_ws,
                              size_t ws_size, hipStream_t stream) {
  const float* stacked = (const float*)d_in[0];
  const float* w_attn = (const float*)d_in[1];
  const float* b_attn = (const float*)d_in[2];
  const float* w_proj = (const float*)d_in[3];
  const float* b_proj = (const float*)d_in[4];
  float* out = (float*)d_out;

  unsigned short* Abf = (unsigned short*)d_ws;            // 4096x1024 bf16
  unsigned short* WaT = Abf + (size_t)M_ * E_;            // 3072x1024 bf16
  unsigned short* WpT = WaT + (size_t)N3E * E_;           // 1024x1024 bf16
  unsigned short* qkv = WpT + (size_t)E_ * E_;            // 4096x3072 bf16
  unsigned short* aout = qkv + (size_t)M_ * N3E;          // 4096x1024 bf16
  unsigned short* Vt = aout + (size_t)M_ * E_;            // 2x1024x2048 bf16

  prep_kernel<<<6144, 256, 0, stream>>>(stacked, w_attn, w_proj, Abf, WaT, WpT);
  gemm256<<<(M_ / 256) * (N3E / 192), 512, 0, stream>>>(Abf, WaT, b_attn, qkv,
                                                        Vt, M_, N3E, E_);
  attn_kernel<<<dim3(T_ / 128, NH, B_), 256, 0, stream>>>(qkv, Vt, aout);
  gemm_bt<1><<<(M_ / 128) * (E_ / 128), 256, 0, stream>>>(aout, WpT, b_proj,
                                                          out, M_, E_, E_);
}